// Round 2
// baseline (87.951 us; speedup 1.0000x reference)
//
#include <hip/hip_runtime.h>
#include <stdint.h>

// Problem constants
#define NB 32768   // batch
#define NN 128     // stages (K of the GEMM)
#define NM 32      // multi-pufs
#define NCOLS 768  // 256 x-arb + 256 S1 + 256 S2

typedef __attribute__((ext_vector_type(8))) short bf16x8;
typedef __attribute__((ext_vector_type(4))) float f32x4;

__device__ __forceinline__ uint16_t f2bf(float v) {
    uint32_t u = __float_as_uint(v);
    u += 0x7FFF + ((u >> 16) & 1);   // RNE
    return (uint16_t)(u >> 16);
}

// Build combined, bf16, XOR-swizzled weight matrix Wc[768][128] in workspace.
//  c <256        : Wx[c][k]
//  256<=c<512    : S1 weights: Wy[mk][k] for k<=64 else 0
//  512<=c<768    : S2 weights: Wy[mk][k+1] for k>=64 else 0   (const Wy[mk][129] in epilogue)
// Swizzle: within each 64-element (128B) half, elem ^= ((c&7)<<3)  [T2 bank-conflict fix]
__global__ void puf_prep(const float* __restrict__ Wx, const float* __restrict__ Wy,
                         uint16_t* __restrict__ Wc) {
    int idx = blockIdx.x * 256 + threadIdx.x;
    if (idx >= NCOLS * NN) return;
    int c = idx >> 7, k = idx & 127;
    float v;
    if (c < 256) {
        v = Wx[c * NN + k];
    } else if (c < 512) {
        int mk = c - 256;
        v = (k <= 64) ? Wy[mk * 130 + k] : 0.0f;
    } else {
        int mk = c - 512;
        v = (k >= 64) ? Wy[mk * 130 + k + 1] : 0.0f;
    }
    int swz = (k & 64) | ((k & 63) ^ ((c & 7) << 3));
    Wc[c * NN + swz] = f2bf(v);
}

__global__ __launch_bounds__(512, 2) void puf_main(
    const float* __restrict__ x, const float* __restrict__ bx,
    const float* __restrict__ Wy, const uint16_t* __restrict__ Wc,
    float* __restrict__ out)
{
    __shared__ uint16_t As[128 * 128];  // 32KB phi tile (swizzled)
    __shared__ uint16_t Bs[512 * 64];   // 64KB weight tile (B1:[256][128], B2:[512][64])
    __shared__ float    Xo[128 * 32];   // 16KB x_out[row][m]

    const int tid = threadIdx.x;
    const int w   = tid >> 6, l = tid & 63;
    const int wr  = w >> 2, wc = w & 3;     // row-half / col-quarter of this wave
    const int l15 = l & 15, l4 = l >> 4;
    const int row0 = blockIdx.x * 128;

    // early scattered loads (L2): bias + S2 constant per col-fragment
    float bxv[4], epsv[4];
#pragma unroll
    for (int cf = 0; cf < 4; ++cf) {
        int c = wc * 64 + cf * 16 + l15;
        bxv[cf]  = bx[c];
        epsv[cf] = Wy[c * 130 + 129];
    }

    // ---------------- Phase A: phi features via ballot parity ----------------
    float xa[16], xb[16];
#pragma unroll
    for (int i = 0; i < 16; ++i) {
        int grow = row0 + w * 16 + i;
        xa[i] = x[grow * NN + l];
        xb[i] = x[grow * NN + 64 + l];
    }
#pragma unroll
    for (int i = 0; i < 16; ++i) {
        int r = w * 16 + i;
        unsigned long long m0 = __ballot(xa[i] > 0.5f);  // bits: x[r][0..63]
        unsigned long long m1 = __ballot(xb[i] > 0.5f);  // bits: x[r][64..127]
        int onesHi = __popcll(m1);
        int parLo = (__popcll(m0 >> l) + onesHi) & 1;    // parity of x[r][l..127]
        int parHi = (__popcll(m1 >> l)) & 1;             // parity of x[r][64+l..127]
        uint16_t blo = parLo ? 0xBF80u : 0x3F80u;        // -1 / +1 in bf16
        uint16_t bhi = parHi ? 0xBF80u : 0x3F80u;
        int sw = (r & 7) << 3;
        As[r * 128 + (l ^ sw)]        = blo;             // elem l
        As[r * 128 + (64 + (l ^ sw))] = bhi;             // elem 64+l
    }

    // stage B1 weights: Wc rows [0,256) -> Bs (linear 64KB copy, swizzle pre-baked)
    {
        const uint4* src = (const uint4*)Wc;
        uint4* dst = (uint4*)Bs;
#pragma unroll
        for (int it = 0; it < 8; ++it) {
            int o = it * 512 + tid;
            dst[o] = src[o];
        }
    }
    __syncthreads();

    // ---------------- B1 GEMM: x-arbiter cols [0,256) ----------------
    const f32x4 zero4 = {0.0f, 0.0f, 0.0f, 0.0f};
    f32x4 acc1[4][4];
#pragma unroll
    for (int a = 0; a < 4; ++a)
#pragma unroll
        for (int b = 0; b < 4; ++b) acc1[a][b] = zero4;

#pragma unroll
    for (int t = 0; t < 4; ++t) {
        int k = t * 32 + l4 * 8;
        bf16x8 af[4], bf[4];
#pragma unroll
        for (int rf = 0; rf < 4; ++rf) {
            int r = wr * 64 + rf * 16 + l15;
            af[rf] = *(const bf16x8*)&As[r * 128 + ((k & 64) | ((k & 63) ^ ((r & 7) << 3)))];
        }
#pragma unroll
        for (int cf = 0; cf < 4; ++cf) {
            int c = wc * 64 + cf * 16 + l15;
            bf[cf] = *(const bf16x8*)&Bs[c * 128 + ((k & 64) | ((k & 63) ^ ((c & 7) << 3)))];
        }
#pragma unroll
        for (int rf = 0; rf < 4; ++rf)
#pragma unroll
            for (int cf = 0; cf < 4; ++cf)
                acc1[rf][cf] = __builtin_amdgcn_mfma_f32_16x16x32_bf16(af[rf], bf[cf], acc1[rf][cf], 0, 0, 0);
    }
    __syncthreads();  // all waves done reading Bs (B1 tile)

    // issue B2 half-0 stage loads early (hide under epilogue VALU)
    uint4 stg[8];
#pragma unroll
    for (int it = 0; it < 8; ++it) {
        int c = it * 64 + (tid >> 3);
        stg[it] = *(const uint4*)&Wc[(256 + c) * 128 + (tid & 7) * 8];
    }

    // ---------------- B1 epilogue: x_out -> Xo (wave-local) ----------------
#pragma unroll
    for (int rf = 0; rf < 4; ++rf) {
#pragma unroll
        for (int cf = 0; cf < 4; ++cf) {
            float p[4];
#pragma unroll
            for (int q = 0; q < 4; ++q) p[q] = acc1[rf][cf][q] + bxv[cf];
#pragma unroll
            for (int q = 0; q < 4; ++q) {
                p[q] *= __shfl_xor(p[q], 1);
                p[q] *= __shfl_xor(p[q], 2);
                p[q] *= __shfl_xor(p[q], 4);
            }
            if ((l & 7) == 0) {
                int m = wc * 8 + cf * 2 + (l15 >> 3);
#pragma unroll
                for (int q = 0; q < 4; ++q) {
                    int r = wr * 64 + rf * 16 + l4 * 4 + q;
                    float sig = 1.0f / (1.0f + __expf(-p[q]));
                    Xo[r * 32 + m] = 1.0f - 2.0f * sig;
                }
            }
        }
    }

    // write staged half-0
#pragma unroll
    for (int it = 0; it < 8; ++it) {
        int c = it * 64 + (tid >> 3);
        *(uint4*)&Bs[c * 64 + (tid & 7) * 8] = stg[it];
    }
    __syncthreads();

    // ---------------- B2 GEMM: S1 (tile rows 0..255) and S2 (256..511) ----------------
    f32x4 accS1[4][4], accS2[4][4];
#pragma unroll
    for (int a = 0; a < 4; ++a)
#pragma unroll
        for (int b = 0; b < 4; ++b) { accS1[a][b] = zero4; accS2[a][b] = zero4; }

#pragma unroll
    for (int h = 0; h < 2; ++h) {
        if (h == 1) {
            __syncthreads();  // done reading half-0
#pragma unroll
            for (int it = 0; it < 8; ++it) {
                int c = it * 64 + (tid >> 3);
                stg[it] = *(const uint4*)&Wc[(256 + c) * 128 + 64 + (tid & 7) * 8];
            }
#pragma unroll
            for (int it = 0; it < 8; ++it) {
                int c = it * 64 + (tid >> 3);
                *(uint4*)&Bs[c * 64 + (tid & 7) * 8] = stg[it];
            }
            __syncthreads();
        }
#pragma unroll
        for (int t = 0; t < 2; ++t) {
            int kk = t * 32 + l4 * 8;     // k within half [0,64)
            int ka = h * 64 + kk;         // absolute k for A
            bf16x8 af[4], b1[4], b2[4];
#pragma unroll
            for (int rf = 0; rf < 4; ++rf) {
                int r = wr * 64 + rf * 16 + l15;
                af[rf] = *(const bf16x8*)&As[r * 128 + ((ka & 64) | ((ka & 63) ^ ((r & 7) << 3)))];
            }
#pragma unroll
            for (int cf = 0; cf < 4; ++cf) {
                int c1 = wc * 64 + cf * 16 + l15;   // S1 tile row
                int c2 = 256 + c1;                   // S2 tile row (same swizzle: +256 keeps c&7)
                b1[cf] = *(const bf16x8*)&Bs[c1 * 64 + (kk ^ ((c1 & 7) << 3))];
                b2[cf] = *(const bf16x8*)&Bs[c2 * 64 + (kk ^ ((c1 & 7) << 3))];
            }
#pragma unroll
            for (int rf = 0; rf < 4; ++rf)
#pragma unroll
                for (int cf = 0; cf < 4; ++cf) {
                    accS1[rf][cf] = __builtin_amdgcn_mfma_f32_16x16x32_bf16(af[rf], b1[cf], accS1[rf][cf], 0, 0, 0);
                    accS2[rf][cf] = __builtin_amdgcn_mfma_f32_16x16x32_bf16(af[rf], b2[cf], accS2[rf][cf], 0, 0, 0);
                }
        }
    }

    // ---------------- B2 epilogue: combine, product over ky, sigmoid, store ----------------
#pragma unroll
    for (int rf = 0; rf < 4; ++rf) {
#pragma unroll
        for (int cf = 0; cf < 4; ++cf) {
            int m = wc * 8 + cf * 2 + (l15 >> 3);
            float p[4];
#pragma unroll
            for (int q = 0; q < 4; ++q) {
                int r = wr * 64 + rf * 16 + l4 * 4 + q;
                float xo  = Xo[r * 32 + m];
                float axo = fabsf(xo);
                float s1 = accS1[rf][cf][q];
                float s2 = accS2[rf][cf][q] + epsv[cf];
                p[q] = xo * s1 + axo * s2;
            }
#pragma unroll
            for (int q = 0; q < 4; ++q) {
                p[q] *= __shfl_xor(p[q], 1);
                p[q] *= __shfl_xor(p[q], 2);
                p[q] *= __shfl_xor(p[q], 4);
            }
            if ((l & 7) == 0) {
                f32x4 o;
#pragma unroll
                for (int q = 0; q < 4; ++q) o[q] = 1.0f / (1.0f + __expf(-p[q]));
                int rbase = row0 + wr * 64 + rf * 16 + l4 * 4;
                *(f32x4*)&out[m * NB + rbase] = o;
            }
        }
    }
}

extern "C" void kernel_launch(void* const* d_in, const int* in_sizes, int n_in,
                              void* d_out, int out_size, void* d_ws, size_t ws_size,
                              hipStream_t stream) {
    const float* x  = (const float*)d_in[0];
    const float* Wx = (const float*)d_in[1];
    const float* bx = (const float*)d_in[2];
    const float* Wy = (const float*)d_in[3];
    float* out = (float*)d_out;
    uint16_t* Wc = (uint16_t*)d_ws;   // 768*128*2 = 196608 bytes

    puf_prep<<<dim3(384), dim3(256), 0, stream>>>(Wx, Wy, Wc);
    puf_main<<<dim3(256), dim3(512), 0, stream>>>(x, bx, Wy, Wc, out);
}